// Round 6
// baseline (858.719 us; speedup 1.0000x reference)
//
#include <hip/hip_runtime.h>
#include <hip/hip_bf16.h>

#define NN 100000
#define NE 600000
#define HH 128
#define NB 4
#define TILE 2048
#define NTILES ((NN + TILE - 1) / TILE)   // 49

typedef __attribute__((ext_vector_type(8))) short bf16x8;
typedef __attribute__((ext_vector_type(4))) float f32x4;
typedef __attribute__((ext_vector_type(4))) float vfloat4;
typedef __attribute__((ext_vector_type(4))) unsigned short ushort4v;

// round-to-nearest-even f32 -> bf16 bits (inputs are finite)
static __device__ __forceinline__ short f2bf(float f) {
  unsigned u = __float_as_uint(f);
  unsigned r = (u + 0x7fffu + ((u >> 16) & 1u)) >> 16;
  return (short)r;
}

static __device__ __forceinline__ float bf2f(short s) {
  unsigned u = (unsigned)(unsigned short)s;
  return __uint_as_float(u << 16);
}

// W8[kb][o][j] = W[o][k=kb*8+j], kb in [0,80), o in [0,128), j in [0,8).
// W[o][k]: k<512 -> V[k>>7][k&127][o] (= V flat [k*128+o]); else loopW[k-512][o].
// This k-tiled layout makes the MFMA operand-1 fragment load COALESCED:
// lane r reads slot kb*128 + (ct*16 + r)  -> 16 consecutive 16B slots.
__global__ __launch_bounds__(256) void build_wt(const float* __restrict__ V,
                                                const float* __restrict__ loopW,
                                                short* __restrict__ W8)
{
  int idx = blockIdx.x * blockDim.x + threadIdx.x;   // 320*256 = 81920
  int j  = idx & 7;
  int o  = (idx >> 3) & 127;
  int kb = idx >> 10;
  int k  = kb * 8 + j;
  float v;
  if (k < 512) v = V[(size_t)k * HH + o];
  else         v = loopW[(size_t)(k - 512) * HH + o];
  W8[idx] = f2bf(v);
}

// hbf = bf16(emb), vectorized (8 elems/thread/iter)
__global__ __launch_bounds__(256) void cast_h(const float* __restrict__ in,
                                              short* __restrict__ out)
{
  const int n8 = NN * HH / 8;
  for (int i = blockIdx.x * blockDim.x + threadIdx.x; i < n8; i += gridDim.x * blockDim.x) {
    const vfloat4* p = reinterpret_cast<const vfloat4*>(in + i * 8);
    vfloat4 a = p[0], b = p[1];
    bf16x8 o;
#pragma unroll
    for (int j = 0; j < 4; ++j) { o[j] = f2bf(a[j]); o[j + 4] = f2bf(b[j]); }
    reinterpret_cast<bf16x8*>(out)[i] = o;
  }
}

// ---------------- CSR build ----------------

__global__ __launch_bounds__(256) void hist_deg(const int* __restrict__ dst,
                                                int* __restrict__ deg)
{
  int e = blockIdx.x * blockDim.x + threadIdx.x;
  if (e < NE) atomicAdd(&deg[dst[e]], 1);
}

__global__ __launch_bounds__(256) void scan_tiles(const int* __restrict__ deg,
                                                  int* __restrict__ tilesum)
{
  __shared__ int red[256];
  const int tid = threadIdx.x;
  int base = blockIdx.x * TILE + tid * 8;
  int s = 0;
#pragma unroll
  for (int j = 0; j < 8; ++j) {
    int i = base + j;
    if (i < NN) s += deg[i];
  }
  red[tid] = s;
  __syncthreads();
  for (int off = 128; off > 0; off >>= 1) {
    if (tid < off) red[tid] += red[tid + off];
    __syncthreads();
  }
  if (tid == 0) tilesum[blockIdx.x] = red[0];
}

__global__ __launch_bounds__(256) void scan_final(const int* deg,
                                                  const int* __restrict__ tilesum,
                                                  int* __restrict__ rowptr,
                                                  int* cursor)
{
  __shared__ int lds[256];
  const int tid = threadIdx.x;
  int pre = 0;
  for (int t = 0; t < NTILES; ++t)
    if (t < blockIdx.x) pre += tilesum[t];

  int base = blockIdx.x * TILE + tid * 8;
  int d[8];
  int s = 0;
#pragma unroll
  for (int j = 0; j < 8; ++j) {
    int i = base + j;
    d[j] = (i < NN) ? deg[i] : 0;
    s += d[j];
  }
  lds[tid] = s;
  __syncthreads();
  for (int off = 1; off < 256; off <<= 1) {
    int t = (tid >= off) ? lds[tid - off] : 0;
    __syncthreads();
    lds[tid] += t;
    __syncthreads();
  }
  int run = pre + lds[tid] - s;
#pragma unroll
  for (int j = 0; j < 8; ++j) {
    int i = base + j;
    if (i < NN) {
      rowptr[i] = run;
      cursor[i] = run;
      run += d[j];
    }
  }
  if (blockIdx.x == NTILES - 1 && tid == 255)
    rowptr[NN] = pre + lds[255];
}

__global__ __launch_bounds__(256) void scatter_edges(
    const int* __restrict__ src, const int* __restrict__ dst, const int* __restrict__ ety,
    int* __restrict__ cursor, int* __restrict__ csr)
{
  int e = blockIdx.x * blockDim.x + threadIdx.x;
  if (e >= NE) return;
  int d = dst[e];
  int p = atomicAdd(&cursor[d], 1);
  csr[p] = src[e] | (ety[e] << 20);            // src:20 bits, ety:3 bits
}

// ---------------- Gather in h-space ----------------
// One wave per dst node. g[d][b*128+i] = sum_{e->d} comp[et_e][b] * h[src_e][i].
__global__ __launch_bounds__(256) void gather_g(
    const int* __restrict__ rowptr, const int* __restrict__ csr,
    const float* __restrict__ comp,   // [R,B]
    const short* __restrict__ hbf,    // [N,128] bf16 bits
    short* __restrict__ g)            // [N,512] bf16 bits
{
  int wid = (int)(blockIdx.x * 4 + (threadIdx.x >> 6));
  wid = __builtin_amdgcn_readfirstlane(wid);
  if (wid >= NN) return;
  const int lane = threadIdx.x & 63;
  const int b = lane >> 4;
  const int q = lane & 15;

  const int start = rowptr[wid];
  const int end = rowptr[wid + 1];

  float acc[8] = {0.f, 0.f, 0.f, 0.f, 0.f, 0.f, 0.f, 0.f};
  int i = start;
  for (; i + 2 <= end; i += 2) {
    int e0 = csr[i], e1 = csr[i + 1];
    const bf16x8* p0 = reinterpret_cast<const bf16x8*>(hbf + (size_t)(e0 & 0xFFFFF) * HH);
    const bf16x8* p1 = reinterpret_cast<const bf16x8*>(hbf + (size_t)(e1 & 0xFFFFF) * HH);
    bf16x8 h0 = p0[q];
    bf16x8 h1 = p1[q];
    float c0 = comp[(e0 >> 20) * NB + b];
    float c1 = comp[(e1 >> 20) * NB + b];
#pragma unroll
    for (int j = 0; j < 8; ++j) acc[j] += bf2f(h0[j]) * c0;
#pragma unroll
    for (int j = 0; j < 8; ++j) acc[j] += bf2f(h1[j]) * c1;
  }
  if (i < end) {
    int e0 = csr[i];
    const bf16x8* p0 = reinterpret_cast<const bf16x8*>(hbf + (size_t)(e0 & 0xFFFFF) * HH);
    bf16x8 h0 = p0[q];
    float c0 = comp[(e0 >> 20) * NB + b];
#pragma unroll
    for (int j = 0; j < 8; ++j) acc[j] += bf2f(h0[j]) * c0;
  }

  bf16x8 o;
#pragma unroll
  for (int j = 0; j < 8; ++j) o[j] = f2bf(acc[j]);
  reinterpret_cast<bf16x8*>(g + (size_t)wid * 512)[lane] = o;
}

// ---------------- Output GEMM ----------------
// out[n][o] = sum_k A[n][k] * W[o][k],  A = [g (512) | hbf (128)], K=640.
// W8 k-tiled layout -> coalesced operand-1 fragment loads.
// D mapping (verified): node = lane&15, o = ct*16 + (lane>>4)*4 + reg.
// FINAL=0: store bf16(relu(x+bias)) -> next layer's hbf.  FINAL=1: fp32 x+bias.
template<int FINAL>
__global__ __launch_bounds__(256) void gemm_out(
    const short* __restrict__ g,      // [N,512] bf16
    const short* __restrict__ hbf,    // [N,128] bf16
    const short* __restrict__ W8,     // [80][128][8] bf16
    const float* __restrict__ bias,   // [128]
    short* __restrict__ outH,         // [N,128] bf16 (FINAL=0)
    float* __restrict__ outF)         // [N,128] fp32 (FINAL=1)
{
  const int wave = threadIdx.x >> 6;
  const int lane = threadIdx.x & 63;
  const int t0 = blockIdx.x * 128 + wave * 16;
  if (t0 >= NN) return;
  const int t1 = t0 + 64;
  const bool v1 = (t1 < NN);                   // NN % 16 == 0, full tiles
  const int r = lane & 15;
  const int g8 = lane >> 4;

  f32x4 acc0[8], acc1[8];
#pragma unroll
  for (int ct = 0; ct < 8; ++ct) {
    acc0[ct] = (f32x4){0.f, 0.f, 0.f, 0.f};
    acc1[ct] = (f32x4){0.f, 0.f, 0.f, 0.f};
  }

  const bf16x8* ga0 = reinterpret_cast<const bf16x8*>(g + (size_t)(t0 + r) * 512);
  const bf16x8* ga1 = reinterpret_cast<const bf16x8*>(g + (size_t)(t1 + r) * 512);
  const bf16x8* ha0 = reinterpret_cast<const bf16x8*>(hbf + (size_t)(t0 + r) * HH);
  const bf16x8* ha1 = reinterpret_cast<const bf16x8*>(hbf + (size_t)(t1 + r) * HH);
  const bf16x8* wv = reinterpret_cast<const bf16x8*>(W8);   // slot = kb*128 + o

#pragma unroll 2
  for (int ks = 0; ks < 16; ++ks) {            // K-steps over g (k = 0..511)
    bf16x8 a0 = ga0[ks * 4 + g8];
    bf16x8 a1 = v1 ? ga1[ks * 4 + g8] : a0;
    const int kb = ks * 4 + g8;
#pragma unroll
    for (int ct = 0; ct < 8; ++ct) {
      bf16x8 w = wv[(size_t)kb * 128 + ct * 16 + r];
      acc0[ct] = __builtin_amdgcn_mfma_f32_16x16x32_bf16(w, a0, acc0[ct], 0, 0, 0);
      if (v1)
        acc1[ct] = __builtin_amdgcn_mfma_f32_16x16x32_bf16(w, a1, acc1[ct], 0, 0, 0);
    }
  }
#pragma unroll
  for (int ks = 16; ks < 20; ++ks) {           // K-steps over hbf (k = 512..639)
    bf16x8 a0 = ha0[(ks - 16) * 4 + g8];
    bf16x8 a1 = v1 ? ha1[(ks - 16) * 4 + g8] : a0;
    const int kb = ks * 4 + g8;
#pragma unroll
    for (int ct = 0; ct < 8; ++ct) {
      bf16x8 w = wv[(size_t)kb * 128 + ct * 16 + r];
      acc0[ct] = __builtin_amdgcn_mfma_f32_16x16x32_bf16(w, a0, acc0[ct], 0, 0, 0);
      if (v1)
        acc1[ct] = __builtin_amdgcn_mfma_f32_16x16x32_bf16(w, a1, acc1[ct], 0, 0, 0);
    }
  }

#pragma unroll
  for (int ct = 0; ct < 8; ++ct) {
    const int o = ct * 16 + g8 * 4;
    vfloat4 bs = *reinterpret_cast<const vfloat4*>(bias + o);
    if (FINAL) {
      vfloat4 x0, x1;
#pragma unroll
      for (int rr = 0; rr < 4; ++rr) { x0[rr] = acc0[ct][rr] + bs[rr]; x1[rr] = acc1[ct][rr] + bs[rr]; }
      reinterpret_cast<vfloat4*>(outF + (size_t)(t0 + r) * HH)[ct * 4 + g8] = x0;
      if (v1) reinterpret_cast<vfloat4*>(outF + (size_t)(t1 + r) * HH)[ct * 4 + g8] = x1;
    } else {
      ushort4v s0, s1;
#pragma unroll
      for (int rr = 0; rr < 4; ++rr) {
        s0[rr] = (unsigned short)f2bf(fmaxf(acc0[ct][rr] + bs[rr], 0.f));
        s1[rr] = (unsigned short)f2bf(fmaxf(acc1[ct][rr] + bs[rr], 0.f));
      }
      reinterpret_cast<ushort4v*>(outH + (size_t)(t0 + r) * HH)[ct * 4 + g8] = s0;
      if (v1) reinterpret_cast<ushort4v*>(outH + (size_t)(t1 + r) * HH)[ct * 4 + g8] = s1;
    }
  }
}

extern "C" void kernel_launch(void* const* d_in, const int* in_sizes, int n_in,
                              void* d_out, int out_size, void* d_ws, size_t ws_size,
                              hipStream_t stream)
{
  const int*   srcp  = (const int*)d_in[1];
  const int*   dstp  = (const int*)d_in[2];
  const int*   etp   = (const int*)d_in[3];
  const float* emb   = (const float*)d_in[4];
  const float* V1    = (const float*)d_in[5];
  const float* comp1 = (const float*)d_in[6];
  const float* loop1 = (const float*)d_in[7];
  const float* bias1 = (const float*)d_in[8];
  const float* V2    = (const float*)d_in[9];
  const float* comp2 = (const float*)d_in[10];
  const float* loop2 = (const float*)d_in[11];
  const float* bias2 = (const float*)d_in[12];
  float* out = (float*)d_out;

  char* ws = (char*)d_ws;
  short* Wt1     = (short*)(ws);                         // 163,840 B
  short* Wt2     = (short*)(ws + 163840);                // 163,840 B
  short* hbf1    = (short*)(ws + 327680);                // 25,600,000 B
  short* hbf2    = (short*)(ws + 25927680);              // 25,600,000 B
  short* g       = (short*)(ws + 51527680);              // 102,400,000 B
  int*   deg     = (int*)  (ws + 153927680);             // 400,000 B (doubles as cursor)
  int*   rowptr  = (int*)  (ws + 154327680);             // 400,004 B
  int*   csr     = (int*)  (ws + 154727696);             // 2,400,000 B
  int*   tilesum = (int*)  (ws + 157127696);             // 196 B

  const int gemm_blocks = (NN + 127) / 128;
  const int agg_blocks  = (NN + 3) / 4;
  const int e_blocks    = (NE + 255) / 256;

  // --- CSR build (once, reused by both layers) ---
  hipMemsetAsync(deg, 0, NN * sizeof(int), stream);
  hipLaunchKernelGGL(hist_deg, dim3(e_blocks), dim3(256), 0, stream, dstp, deg);
  hipLaunchKernelGGL(scan_tiles, dim3(NTILES), dim3(256), 0, stream, deg, tilesum);
  hipLaunchKernelGGL(scan_final, dim3(NTILES), dim3(256), 0, stream,
                     deg, tilesum, rowptr, deg);
  hipLaunchKernelGGL(scatter_edges, dim3(e_blocks), dim3(256), 0, stream,
                     srcp, dstp, etp, deg, csr);

  hipLaunchKernelGGL(build_wt, dim3(320), dim3(256), 0, stream, V1, loop1, Wt1);
  hipLaunchKernelGGL(build_wt, dim3(320), dim3(256), 0, stream, V2, loop2, Wt2);
  hipLaunchKernelGGL(cast_h, dim3(2048), dim3(256), 0, stream, emb, hbf1);

  // Layer 1: gather raw-h basis sums, then fused basis-combine+selfloop+bias+relu
  hipLaunchKernelGGL(gather_g, dim3(agg_blocks), dim3(256), 0, stream,
                     rowptr, csr, comp1, hbf1, g);
  hipLaunchKernelGGL((gemm_out<0>), dim3(gemm_blocks), dim3(256), 0, stream,
                     g, hbf1, Wt1, bias1, hbf2, (float*)nullptr);

  // Layer 2: same, final fp32 output (no relu)
  hipLaunchKernelGGL(gather_g, dim3(agg_blocks), dim3(256), 0, stream,
                     rowptr, csr, comp2, hbf2, g);
  hipLaunchKernelGGL((gemm_out<1>), dim3(gemm_blocks), dim3(256), 0, stream,
                     g, hbf2, Wt2, bias2, (short*)nullptr, out);
}

// Round 7
// 295.444 us; speedup vs baseline: 2.9065x; 2.9065x over previous
//
#include <hip/hip_runtime.h>
#include <hip/hip_bf16.h>

#define NN 100000
#define NE 600000
#define HH 128
#define NB 4
#define TILE 2048
#define NTILES ((NN + TILE - 1) / TILE)   // 49

typedef __attribute__((ext_vector_type(8))) short bf16x8;
typedef __attribute__((ext_vector_type(4))) float f32x4;
typedef __attribute__((ext_vector_type(4))) float vfloat4;
typedef __attribute__((ext_vector_type(4))) unsigned short ushort4v;

// round-to-nearest-even f32 -> bf16 bits (inputs are finite)
static __device__ __forceinline__ short f2bf(float f) {
  unsigned u = __float_as_uint(f);
  unsigned r = (u + 0x7fffu + ((u >> 16) & 1u)) >> 16;
  return (short)r;
}

static __device__ __forceinline__ float bf2f(short s) {
  unsigned u = (unsigned)(unsigned short)s;
  return __uint_as_float(u << 16);
}

// W8[kb][o][j] = W[o][k=kb*8+j], kb in [0,80), o in [0,128), j in [0,8).
// W[o][k]: k<512 -> V[k>>7][k&127][o] (= V flat [k*128+o]); else loopW[k-512][o].
__global__ __launch_bounds__(256) void build_wt(const float* __restrict__ V,
                                                const float* __restrict__ loopW,
                                                short* __restrict__ W8)
{
  int idx = blockIdx.x * blockDim.x + threadIdx.x;   // 320*256 = 81920
  int j  = idx & 7;
  int o  = (idx >> 3) & 127;
  int kb = idx >> 10;
  int k  = kb * 8 + j;
  float v;
  if (k < 512) v = V[(size_t)k * HH + o];
  else         v = loopW[(size_t)(k - 512) * HH + o];
  W8[idx] = f2bf(v);
}

// hbf = bf16(emb), vectorized (8 elems/thread/iter)
__global__ __launch_bounds__(256) void cast_h(const float* __restrict__ in,
                                              short* __restrict__ out)
{
  const int n8 = NN * HH / 8;
  for (int i = blockIdx.x * blockDim.x + threadIdx.x; i < n8; i += gridDim.x * blockDim.x) {
    const vfloat4* p = reinterpret_cast<const vfloat4*>(in + i * 8);
    vfloat4 a = p[0], b = p[1];
    bf16x8 o;
#pragma unroll
    for (int j = 0; j < 4; ++j) { o[j] = f2bf(a[j]); o[j + 4] = f2bf(b[j]); }
    reinterpret_cast<bf16x8*>(out)[i] = o;
  }
}

// ---------------- CSR build ----------------

__global__ __launch_bounds__(256) void hist_deg(const int* __restrict__ dst,
                                                int* __restrict__ deg)
{
  int e = blockIdx.x * blockDim.x + threadIdx.x;
  if (e < NE) atomicAdd(&deg[dst[e]], 1);
}

__global__ __launch_bounds__(256) void scan_tiles(const int* __restrict__ deg,
                                                  int* __restrict__ tilesum)
{
  __shared__ int red[256];
  const int tid = threadIdx.x;
  int base = blockIdx.x * TILE + tid * 8;
  int s = 0;
#pragma unroll
  for (int j = 0; j < 8; ++j) {
    int i = base + j;
    if (i < NN) s += deg[i];
  }
  red[tid] = s;
  __syncthreads();
  for (int off = 128; off > 0; off >>= 1) {
    if (tid < off) red[tid] += red[tid + off];
    __syncthreads();
  }
  if (tid == 0) tilesum[blockIdx.x] = red[0];
}

__global__ __launch_bounds__(256) void scan_final(const int* deg,
                                                  const int* __restrict__ tilesum,
                                                  int* __restrict__ rowptr,
                                                  int* cursor)
{
  __shared__ int lds[256];
  const int tid = threadIdx.x;
  int pre = 0;
  for (int t = 0; t < NTILES; ++t)
    if (t < blockIdx.x) pre += tilesum[t];

  int base = blockIdx.x * TILE + tid * 8;
  int d[8];
  int s = 0;
#pragma unroll
  for (int j = 0; j < 8; ++j) {
    int i = base + j;
    d[j] = (i < NN) ? deg[i] : 0;
    s += d[j];
  }
  lds[tid] = s;
  __syncthreads();
  for (int off = 1; off < 256; off <<= 1) {
    int t = (tid >= off) ? lds[tid - off] : 0;
    __syncthreads();
    lds[tid] += t;
    __syncthreads();
  }
  int run = pre + lds[tid] - s;
#pragma unroll
  for (int j = 0; j < 8; ++j) {
    int i = base + j;
    if (i < NN) {
      rowptr[i] = run;
      cursor[i] = run;
      run += d[j];
    }
  }
  if (blockIdx.x == NTILES - 1 && tid == 255)
    rowptr[NN] = pre + lds[255];
}

__global__ __launch_bounds__(256) void scatter_edges(
    const int* __restrict__ src, const int* __restrict__ dst, const int* __restrict__ ety,
    int* __restrict__ cursor, int* __restrict__ csr)
{
  int e = blockIdx.x * blockDim.x + threadIdx.x;
  if (e >= NE) return;
  int d = dst[e];
  int p = atomicAdd(&cursor[d], 1);
  csr[p] = src[e] | (ety[e] << 20);            // src:20 bits, ety:3 bits
}

// ---------------- Gather in h-space ----------------
// One wave per dst node. g[d][b*128+i] = sum_{e->d} comp[et_e][b] * h[src_e][i].
__global__ __launch_bounds__(256) void gather_g(
    const int* __restrict__ rowptr, const int* __restrict__ csr,
    const float* __restrict__ comp,   // [R,B]
    const short* __restrict__ hbf,    // [N,128] bf16 bits
    short* __restrict__ g)            // [N,512] bf16 bits
{
  int wid = (int)(blockIdx.x * 4 + (threadIdx.x >> 6));
  wid = __builtin_amdgcn_readfirstlane(wid);
  if (wid >= NN) return;
  const int lane = threadIdx.x & 63;
  const int b = lane >> 4;
  const int q = lane & 15;

  const int start = rowptr[wid];
  const int end = rowptr[wid + 1];

  float acc[8] = {0.f, 0.f, 0.f, 0.f, 0.f, 0.f, 0.f, 0.f};
  int i = start;
  for (; i + 2 <= end; i += 2) {
    int e0 = csr[i], e1 = csr[i + 1];
    const bf16x8* p0 = reinterpret_cast<const bf16x8*>(hbf + (size_t)(e0 & 0xFFFFF) * HH);
    const bf16x8* p1 = reinterpret_cast<const bf16x8*>(hbf + (size_t)(e1 & 0xFFFFF) * HH);
    bf16x8 h0 = p0[q];
    bf16x8 h1 = p1[q];
    float c0 = comp[(e0 >> 20) * NB + b];
    float c1 = comp[(e1 >> 20) * NB + b];
#pragma unroll
    for (int j = 0; j < 8; ++j) acc[j] += bf2f(h0[j]) * c0;
#pragma unroll
    for (int j = 0; j < 8; ++j) acc[j] += bf2f(h1[j]) * c1;
  }
  if (i < end) {
    int e0 = csr[i];
    const bf16x8* p0 = reinterpret_cast<const bf16x8*>(hbf + (size_t)(e0 & 0xFFFFF) * HH);
    bf16x8 h0 = p0[q];
    float c0 = comp[(e0 >> 20) * NB + b];
#pragma unroll
    for (int j = 0; j < 8; ++j) acc[j] += bf2f(h0[j]) * c0;
  }

  bf16x8 o;
#pragma unroll
  for (int j = 0; j < 8; ++j) o[j] = f2bf(acc[j]);
  reinterpret_cast<bf16x8*>(g + (size_t)wid * 512)[lane] = o;
}

// ---------------- Output GEMM (LDS-staged W, double-buffered) ----------------
// out[n][o] = sum_k A[n][k] * W[o][k],  A = [g (512) | hbf (128)], K=640.
// W staged through LDS in 8KB k-slices (T14 order: gload regs early, ds_write,
// one barrier/step). Waves read W fragments via ds_read_b128 (reused 2x by the
// two m-tiles). D mapping (verified): node = lane&15, o = ct*16+(lane>>4)*4+reg.
// NOTE: no early return -- all waves must reach every __syncthreads.
template<int FINAL>
__global__ __launch_bounds__(256) void gemm_out(
    const short* __restrict__ g,      // [N,512] bf16
    const short* __restrict__ hbf,    // [N,128] bf16
    const short* __restrict__ W8,     // [80][128][8] bf16 (slot = kb*128+o)
    const float* __restrict__ bias,   // [128]
    short* __restrict__ outH,         // [N,128] bf16 (FINAL=0)
    float* __restrict__ outF)         // [N,128] fp32 (FINAL=1)
{
  __shared__ bf16x8 wlds[2][512];     // 16 KB: two 8KB k-slices (4 kb x 128 o)

  const int tid  = threadIdx.x;
  const int wave = tid >> 6;
  const int lane = tid & 63;
  const int t0 = blockIdx.x * 128 + wave * 16;
  const int t1 = t0 + 64;
  const bool valid0 = (t0 < NN);
  const bool valid1 = (t1 < NN);
  const int r  = lane & 15;
  const int g8 = lane >> 4;

  const size_t row0 = valid0 ? (size_t)(t0 + r) : 0;
  const size_t row1 = valid1 ? (size_t)(t1 + r) : 0;
  const bf16x8* ga0 = reinterpret_cast<const bf16x8*>(g + row0 * 512);
  const bf16x8* ga1 = reinterpret_cast<const bf16x8*>(g + row1 * 512);
  const bf16x8* ha0 = reinterpret_cast<const bf16x8*>(hbf + row0 * HH);
  const bf16x8* ha1 = reinterpret_cast<const bf16x8*>(hbf + row1 * HH);
  const bf16x8* wsrc = reinterpret_cast<const bf16x8*>(W8);

  f32x4 acc0[8], acc1[8];
#pragma unroll
  for (int ct = 0; ct < 8; ++ct) {
    acc0[ct] = (f32x4){0.f, 0.f, 0.f, 0.f};
    acc1[ct] = (f32x4){0.f, 0.f, 0.f, 0.f};
  }

  // prologue: stage slice 0 (512 slots, 2 per thread, coalesced)
  wlds[0][tid]       = wsrc[tid];
  wlds[0][tid + 256] = wsrc[tid + 256];
  __syncthreads();

#pragma unroll 1
  for (int ks = 0; ks < 20; ++ks) {
    const int cur = ks & 1;
    // stage next slice into the other buffer (its readers finished last iter)
    if (ks < 19) {
      bf16x8 n0 = wsrc[(ks + 1) * 512 + tid];
      bf16x8 n1 = wsrc[(ks + 1) * 512 + 256 + tid];
      wlds[cur ^ 1][tid]       = n0;
      wlds[cur ^ 1][tid + 256] = n1;
    }
    // A fragments for this k-slice
    bf16x8 a0 = (ks < 16) ? ga0[ks * 4 + g8] : ha0[(ks - 16) * 4 + g8];
    bf16x8 a1 = (ks < 16) ? ga1[ks * 4 + g8] : ha1[(ks - 16) * 4 + g8];
    // compute: 8 ds_read_b128, each feeds 2 MFMAs
#pragma unroll
    for (int ct = 0; ct < 8; ++ct) {
      bf16x8 w = wlds[cur][g8 * 128 + ct * 16 + r];
      acc0[ct] = __builtin_amdgcn_mfma_f32_16x16x32_bf16(w, a0, acc0[ct], 0, 0, 0);
      acc1[ct] = __builtin_amdgcn_mfma_f32_16x16x32_bf16(w, a1, acc1[ct], 0, 0, 0);
    }
    __syncthreads();   // staged slice visible + cur slice free for overwrite
  }

#pragma unroll
  for (int ct = 0; ct < 8; ++ct) {
    const int o = ct * 16 + g8 * 4;
    vfloat4 bs = *reinterpret_cast<const vfloat4*>(bias + o);
    if (FINAL) {
      vfloat4 x0, x1;
#pragma unroll
      for (int rr = 0; rr < 4; ++rr) { x0[rr] = acc0[ct][rr] + bs[rr]; x1[rr] = acc1[ct][rr] + bs[rr]; }
      if (valid0) reinterpret_cast<vfloat4*>(outF + (size_t)(t0 + r) * HH)[ct * 4 + g8] = x0;
      if (valid1) reinterpret_cast<vfloat4*>(outF + (size_t)(t1 + r) * HH)[ct * 4 + g8] = x1;
    } else {
      ushort4v s0, s1;
#pragma unroll
      for (int rr = 0; rr < 4; ++rr) {
        s0[rr] = (unsigned short)f2bf(fmaxf(acc0[ct][rr] + bs[rr], 0.f));
        s1[rr] = (unsigned short)f2bf(fmaxf(acc1[ct][rr] + bs[rr], 0.f));
      }
      if (valid0) reinterpret_cast<ushort4v*>(outH + (size_t)(t0 + r) * HH)[ct * 4 + g8] = s0;
      if (valid1) reinterpret_cast<ushort4v*>(outH + (size_t)(t1 + r) * HH)[ct * 4 + g8] = s1;
    }
  }
}

extern "C" void kernel_launch(void* const* d_in, const int* in_sizes, int n_in,
                              void* d_out, int out_size, void* d_ws, size_t ws_size,
                              hipStream_t stream)
{
  const int*   srcp  = (const int*)d_in[1];
  const int*   dstp  = (const int*)d_in[2];
  const int*   etp   = (const int*)d_in[3];
  const float* emb   = (const float*)d_in[4];
  const float* V1    = (const float*)d_in[5];
  const float* comp1 = (const float*)d_in[6];
  const float* loop1 = (const float*)d_in[7];
  const float* bias1 = (const float*)d_in[8];
  const float* V2    = (const float*)d_in[9];
  const float* comp2 = (const float*)d_in[10];
  const float* loop2 = (const float*)d_in[11];
  const float* bias2 = (const float*)d_in[12];
  float* out = (float*)d_out;

  char* ws = (char*)d_ws;
  short* Wt1     = (short*)(ws);                         // 163,840 B
  short* Wt2     = (short*)(ws + 163840);                // 163,840 B
  short* hbf1    = (short*)(ws + 327680);                // 25,600,000 B
  short* hbf2    = (short*)(ws + 25927680);              // 25,600,000 B
  short* g       = (short*)(ws + 51527680);              // 102,400,000 B
  int*   deg     = (int*)  (ws + 153927680);             // 400,000 B (doubles as cursor)
  int*   rowptr  = (int*)  (ws + 154327680);             // 400,004 B
  int*   csr     = (int*)  (ws + 154727696);             // 2,400,000 B
  int*   tilesum = (int*)  (ws + 157127696);             // 196 B

  const int gemm_blocks = (NN + 127) / 128;
  const int agg_blocks  = (NN + 3) / 4;
  const int e_blocks    = (NE + 255) / 256;

  // --- CSR build (once, reused by both layers) ---
  hipMemsetAsync(deg, 0, NN * sizeof(int), stream);
  hipLaunchKernelGGL(hist_deg, dim3(e_blocks), dim3(256), 0, stream, dstp, deg);
  hipLaunchKernelGGL(scan_tiles, dim3(NTILES), dim3(256), 0, stream, deg, tilesum);
  hipLaunchKernelGGL(scan_final, dim3(NTILES), dim3(256), 0, stream,
                     deg, tilesum, rowptr, deg);
  hipLaunchKernelGGL(scatter_edges, dim3(e_blocks), dim3(256), 0, stream,
                     srcp, dstp, etp, deg, csr);

  hipLaunchKernelGGL(build_wt, dim3(320), dim3(256), 0, stream, V1, loop1, Wt1);
  hipLaunchKernelGGL(build_wt, dim3(320), dim3(256), 0, stream, V2, loop2, Wt2);
  hipLaunchKernelGGL(cast_h, dim3(2048), dim3(256), 0, stream, emb, hbf1);

  // Layer 1: gather raw-h basis sums, then fused basis-combine+selfloop+bias+relu
  hipLaunchKernelGGL(gather_g, dim3(agg_blocks), dim3(256), 0, stream,
                     rowptr, csr, comp1, hbf1, g);
  hipLaunchKernelGGL((gemm_out<0>), dim3(gemm_blocks), dim3(256), 0, stream,
                     g, hbf1, Wt1, bias1, hbf2, (float*)nullptr);

  // Layer 2: same, final fp32 output (no relu)
  hipLaunchKernelGGL(gather_g, dim3(agg_blocks), dim3(256), 0, stream,
                     rowptr, csr, comp2, hbf2, g);
  hipLaunchKernelGGL((gemm_out<1>), dim3(gemm_blocks), dim3(256), 0, stream,
                     g, hbf2, Wt2, bias2, (short*)nullptr, out);
}